// Round 3
// baseline (173.907 us; speedup 1.0000x reference)
//
#include <hip/hip_runtime.h>

// ---------------------------------------------------------------------------
// DeepLagrangianNetwork head: per-row tiny MLP (4 -> 64 -> 64 -> {2,1}),
// then H = L L^T + 1e-9 I for a 2x2 lower-triangular L.
//   L = [[Ld0, 0], [Lo, Ld1]]  ->  H00=Ld0^2+1e-9, H01=H10=Ld0*Lo,
//                                  H11=Lo^2+Ld1^2+1e-9
// Inputs fp32; OUTPUT fp32 (round-2 evidence: bf16-packed writes gave
// O(max) error -> harness reads d_out as float32). One thread = one row.
// Main kernel has NO bounds check (uniform control flow) so uniform-address
// weight loads can scalarize to s_load -> inner loop is pure v_fmac_f32.
// ---------------------------------------------------------------------------

__device__ __forceinline__ float lrelu(float a) {
    // a>=0 -> a ; a<0 -> 0.01a (0.01a > a for a<0): exact leaky_relu
    return fmaxf(a, 0.01f * a);
}

__device__ __forceinline__ float softplus(float v) {
    // jax.nn.softplus = logaddexp(v,0) = max(v,0) + log1p(exp(-|v|))
    return fmaxf(v, 0.0f) + log1pf(expf(-fabsf(v)));
}

__device__ __forceinline__ void dln_row(
    int row,
    const float* __restrict__ x,
    const float* __restrict__ W1,  const float* __restrict__ b1,
    const float* __restrict__ W2,  const float* __restrict__ b2,
    const float* __restrict__ WLd, const float* __restrict__ bLd,
    const float* __restrict__ WLo, const float* __restrict__ bLo,
    float* __restrict__ out)
{
    // ---- load q: 4 fp32 = 16 B/lane, perfectly coalesced -----------------
    const float4 q = reinterpret_cast<const float4*>(x)[row];

    // ---- layer 1: h1 = lrelu(q . W1^T + b1), 64 outputs ------------------
    float h1[64];
#pragma unroll
    for (int j = 0; j < 64; ++j) {
        float a = b1[j];
        a = fmaf(q.x, W1[4 * j + 0], a);
        a = fmaf(q.y, W1[4 * j + 1], a);
        a = fmaf(q.z, W1[4 * j + 2], a);
        a = fmaf(q.w, W1[4 * j + 3], a);
        h1[j] = lrelu(a);
    }

    // ---- layer 2 fused with the three heads ------------------------------
    float ld0 = bLd[0];
    float ld1 = bLd[1];
    float lo  = bLo[0];

#pragma unroll 4
    for (int j = 0; j < 64; ++j) {
        float a0 = b2[j];
        float a1 = 0.0f;
        const float* __restrict__ w = W2 + 64 * j;
#pragma unroll
        for (int k = 0; k < 64; k += 2) {
            a0 = fmaf(h1[k],     w[k],     a0);
            a1 = fmaf(h1[k + 1], w[k + 1], a1);
        }
        const float a = lrelu(a0 + a1);
        ld0 = fmaf(a, WLd[j],      ld0);
        ld1 = fmaf(a, WLd[64 + j], ld1);
        lo  = fmaf(a, WLo[j],      lo);
    }

    // ---- heads epilogue + H = L L^T + 1e-9 I -----------------------------
    ld0 = softplus(ld0);
    ld1 = softplus(ld1);

    float4 o;
    o.x = fmaf(ld0, ld0, 1e-9f);                  // H00
    o.y = ld0 * lo;                               // H01
    o.z = o.y;                                    // H10
    o.w = fmaf(lo, lo, fmaf(ld1, ld1, 1e-9f));    // H11
    reinterpret_cast<float4*>(out)[row] = o;      // 16 B/lane coalesced
}

__global__ __launch_bounds__(256) void dln_main(
    const float* __restrict__ x,
    const float* __restrict__ W1,  const float* __restrict__ b1,
    const float* __restrict__ W2,  const float* __restrict__ b2,
    const float* __restrict__ WLd, const float* __restrict__ bLd,
    const float* __restrict__ WLo, const float* __restrict__ bLo,
    float* __restrict__ out)
{
    // No bounds check: grid covers exactly (nrows/256) blocks -> uniform CF.
    const int row = blockIdx.x * 256 + threadIdx.x;
    dln_row(row, x, W1, b1, W2, b2, WLd, bLd, WLo, bLo, out);
}

__global__ __launch_bounds__(256) void dln_tail(
    const float* __restrict__ x,
    const float* __restrict__ W1,  const float* __restrict__ b1,
    const float* __restrict__ W2,  const float* __restrict__ b2,
    const float* __restrict__ WLd, const float* __restrict__ bLd,
    const float* __restrict__ WLo, const float* __restrict__ bLo,
    float* __restrict__ out, int row0, int nrows)
{
    const int row = row0 + blockIdx.x * 256 + threadIdx.x;
    if (row < nrows)
        dln_row(row, x, W1, b1, W2, b2, WLd, bLd, WLo, bLo, out);
}

extern "C" void kernel_launch(void* const* d_in, const int* in_sizes, int n_in,
                              void* d_out, int out_size, void* d_ws, size_t ws_size,
                              hipStream_t stream)
{
    const float* x   = (const float*)d_in[0];
    const float* W1  = (const float*)d_in[1];
    const float* b1  = (const float*)d_in[2];
    const float* W2  = (const float*)d_in[3];
    const float* b2  = (const float*)d_in[4];
    const float* WLd = (const float*)d_in[5];
    const float* bLd = (const float*)d_in[6];
    const float* WLo = (const float*)d_in[7];
    const float* bLo = (const float*)d_in[8];
    float* out = (float*)d_out;

    const int nrows = in_sizes[0] / 4;       // x is (nrows, 4) fp32
    const int nfull = nrows / 256;           // full blocks, uniform CF
    const int rem   = nrows - nfull * 256;

    if (nfull > 0)
        dln_main<<<nfull, 256, 0, stream>>>(
            x, W1, b1, W2, b2, WLd, bLd, WLo, bLo, out);
    if (rem > 0)
        dln_tail<<<1, 256, 0, stream>>>(
            x, W1, b1, W2, b2, WLd, bLd, WLo, bLo, out, nfull * 256, nrows);
}

// Round 5
// 130.743 us; speedup vs baseline: 1.3301x; 1.3301x over previous
//
#include <hip/hip_runtime.h>

// ---------------------------------------------------------------------------
// DeepLagrangianNetwork head, MFMA version.
//   per row: h1 = lrelu(q@W1^T+b1)  (4->64, VALU)
//            h2 = lrelu(h1@W2^T+b2) (64->64, bf16 MFMA 16x16x32)
//            heads: Ld (softplus) + Lo (VALU, fp32 weights)
//            H = L L^T + 1e-9 I  (2x2), stored fp32 float4/row.
// Block = 256 threads = 4 waves = 256 rows. LDS holds bf16 h1 (then h2)
// at row stride 72 elements (144 B: 16B-aligned, b128 reads at LDS floor).
// Fragment layouts (m89/m120-verified):
//   A[m=lane&15][k=(lane>>4)*8+j]   B[k=(lane>>4)*8+j][n=lane&15]
//   C: col=lane&15, row=(lane>>4)*4+reg
// Round-4 fix: no __hip_bfloat162 bit_cast (not trivially copyable on this
// ROCm) — pack bf16 pairs with integer RNE directly.
// ---------------------------------------------------------------------------

typedef __attribute__((ext_vector_type(8))) short bf16x8;
typedef __attribute__((ext_vector_type(4))) float f32x4;

#define ROWS_PER_BLOCK 256
#define H_STRIDE 72                 // bf16 elements per LDS row (64 + 8 pad)
#define LDS_SHORTS (ROWS_PER_BLOCK * H_STRIDE)   // 18432 shorts = 36864 B

__device__ __forceinline__ float lrelu(float a) {
    return fmaxf(a, 0.01f * a);     // exact leaky_relu(0.01)
}

__device__ __forceinline__ float softplus(float v) {
    return fmaxf(v, 0.0f) + log1pf(expf(-fabsf(v)));   // jax.nn.softplus
}

__device__ __forceinline__ unsigned short bf16_rne(float f) {
    unsigned u = __float_as_uint(f);
    u += 0x7FFFu + ((u >> 16) & 1u);   // round-to-nearest-even
    return (unsigned short)(u >> 16);
}

__device__ __forceinline__ unsigned pk_bf16(float lo, float hi) {
    // two fp32 -> packed bf16x2 (RNE), lo in bits[15:0]
    return (unsigned)bf16_rne(lo) | ((unsigned)bf16_rne(hi) << 16);
}

__global__ __launch_bounds__(256) void dln_mfma(
    const float* __restrict__ x,
    const float* __restrict__ W1,  const float* __restrict__ b1,
    const float* __restrict__ W2,  const float* __restrict__ b2,
    const float* __restrict__ WLd, const float* __restrict__ bLd,
    const float* __restrict__ WLo, const float* __restrict__ bLo,
    float* __restrict__ out)
{
    __shared__ __align__(16) unsigned short lds[LDS_SHORTS];

    const int tid  = threadIdx.x;
    const int lane = tid & 63;
    const int wv   = tid >> 6;          // wave id 0..3
    const int quad = lane >> 4;         // 0..3
    const int col  = lane & 15;         // 0..15

    // ---- phase 0: stage W2 (fp32, 16 KB) into LDS -------------------------
    {
        const float4* src = (const float4*)W2;          // 1024 float4
        float4*       dst = (float4*)lds;
#pragma unroll
        for (int i = 0; i < 4; ++i)
            dst[tid + 256 * i] = src[tid + 256 * i];
    }
    // per-lane bias for accumulator init: b2[n], n = 16t + col
    float b2c[4];
#pragma unroll
    for (int t = 0; t < 4; ++t) b2c[t] = b2[16 * t + col];
    __syncthreads();

    // ---- build B fragments: B[k][n] = W2[n][k], bf16 ----------------------
    bf16x8 bfrag[4][2];
    {
        const float* w2l = (const float*)lds;
#pragma unroll
        for (int t = 0; t < 4; ++t) {
#pragma unroll
            for (int s = 0; s < 2; ++s) {
                const float* p = w2l + (16 * t + col) * 64 + 32 * s + 8 * quad;
                float4 f0 = *(const float4*)(p);
                float4 f1 = *(const float4*)(p + 4);
                uint4 u;
                u.x = pk_bf16(f0.x, f0.y);
                u.y = pk_bf16(f0.z, f0.w);
                u.z = pk_bf16(f1.x, f1.y);
                u.w = pk_bf16(f1.z, f1.w);
                bfrag[t][s] = __builtin_bit_cast(bf16x8, u);
            }
        }
    }
    __syncthreads();   // W2 region about to be overwritten by h1

    // ---- phase 1: h1 = lrelu(q@W1^T + b1) for row = tid, bf16 -> LDS ------
    const int row_g = blockIdx.x * ROWS_PER_BLOCK + tid;
    {
        const float4 qv = ((const float4*)x)[row_g];
        unsigned short* myrow = lds + tid * H_STRIDE;
#pragma unroll
        for (int blk = 0; blk < 8; ++blk) {
            unsigned up[4];
#pragma unroll
            for (int p = 0; p < 4; ++p) {
                float h[2];
#pragma unroll
                for (int e = 0; e < 2; ++e) {
                    const int j = blk * 8 + p * 2 + e;
                    float a = b1[j];
                    a = fmaf(qv.x, W1[4 * j + 0], a);
                    a = fmaf(qv.y, W1[4 * j + 1], a);
                    a = fmaf(qv.z, W1[4 * j + 2], a);
                    a = fmaf(qv.w, W1[4 * j + 3], a);
                    h[e] = lrelu(a);
                }
                up[p] = pk_bf16(h[0], h[1]);
            }
            *(uint4*)(myrow + blk * 8) = make_uint4(up[0], up[1], up[2], up[3]);
        }
    }
    // No barrier: wave w's M-tiles read only rows [w*64, w*64+64), written by
    // this same wave; per-wave LDS ops are processed in order.

    // ---- phase 2: h2 = lrelu(h1@W2^T + b2) via MFMA, bf16 h2 -> LDS -------
#pragma unroll
    for (int mt = 0; mt < 4; ++mt) {
        const int rbase = wv * 64 + mt * 16;
        // A fragments for K-steps 0 (k=0..31) and 1 (k=32..63)
        const unsigned short* ar = lds + (rbase + col) * H_STRIDE + 8 * quad;
        uint4 a0u = *(const uint4*)(ar);
        uint4 a1u = *(const uint4*)(ar + 32);
        bf16x8 a0 = __builtin_bit_cast(bf16x8, a0u);
        bf16x8 a1 = __builtin_bit_cast(bf16x8, a1u);

        f32x4 acc[4];
#pragma unroll
        for (int t = 0; t < 4; ++t) {
            acc[t] = (f32x4){b2c[t], b2c[t], b2c[t], b2c[t]};
            acc[t] = __builtin_amdgcn_mfma_f32_16x16x32_bf16(a0, bfrag[t][0], acc[t], 0, 0, 0);
            acc[t] = __builtin_amdgcn_mfma_f32_16x16x32_bf16(a1, bfrag[t][1], acc[t], 0, 0, 0);
        }
        // lrelu + store h2 (C layout: row = quad*4+reg, col = 16t+col)
#pragma unroll
        for (int t = 0; t < 4; ++t) {
#pragma unroll
            for (int r = 0; r < 4; ++r) {
                const float v = lrelu(acc[t][r]);
                lds[(rbase + quad * 4 + r) * H_STRIDE + 16 * t + col] = bf16_rne(v);
            }
        }
    }
    __syncthreads();   // h2 visible to all waves

    // ---- phase 3: heads + epilogue, one thread per row --------------------
    {
        const unsigned short* hr = lds + tid * H_STRIDE;
        float ld0 = bLd[0];
        float ld1 = bLd[1];
        float lo  = bLo[0];
#pragma unroll
        for (int i = 0; i < 8; ++i) {
            const uint4 u = *(const uint4*)(hr + i * 8);
            const unsigned uu[4] = {u.x, u.y, u.z, u.w};
#pragma unroll
            for (int p = 0; p < 4; ++p) {
                const int k = i * 8 + p * 2;
                const float e0 = __uint_as_float(uu[p] << 16);
                const float e1 = __uint_as_float(uu[p] & 0xFFFF0000u);
                ld0 = fmaf(e0, WLd[k],          ld0);
                ld0 = fmaf(e1, WLd[k + 1],      ld0);
                ld1 = fmaf(e0, WLd[64 + k],     ld1);
                ld1 = fmaf(e1, WLd[64 + k + 1], ld1);
                lo  = fmaf(e0, WLo[k],          lo);
                lo  = fmaf(e1, WLo[k + 1],      lo);
            }
        }
        ld0 = softplus(ld0);
        ld1 = softplus(ld1);
        float4 o;
        o.x = fmaf(ld0, ld0, 1e-9f);                  // H00
        o.y = ld0 * lo;                               // H01
        o.z = o.y;                                    // H10
        o.w = fmaf(lo, lo, fmaf(ld1, ld1, 1e-9f));    // H11
        reinterpret_cast<float4*>(out)[row_g] = o;
    }
}

// ---- scalar fallback for tail rows (nrows % 256) --------------------------
__global__ __launch_bounds__(256) void dln_tail(
    const float* __restrict__ x,
    const float* __restrict__ W1,  const float* __restrict__ b1,
    const float* __restrict__ W2,  const float* __restrict__ b2,
    const float* __restrict__ WLd, const float* __restrict__ bLd,
    const float* __restrict__ WLo, const float* __restrict__ bLo,
    float* __restrict__ out, int row0, int nrows)
{
    const int row = row0 + blockIdx.x * 256 + threadIdx.x;
    if (row >= nrows) return;
    const float4 qv = reinterpret_cast<const float4*>(x)[row];
    float h1[64];
#pragma unroll
    for (int j = 0; j < 64; ++j) {
        float a = b1[j];
        a = fmaf(qv.x, W1[4 * j + 0], a);
        a = fmaf(qv.y, W1[4 * j + 1], a);
        a = fmaf(qv.z, W1[4 * j + 2], a);
        a = fmaf(qv.w, W1[4 * j + 3], a);
        h1[j] = lrelu(a);
    }
    float ld0 = bLd[0], ld1 = bLd[1], lo = bLo[0];
#pragma unroll 4
    for (int j = 0; j < 64; ++j) {
        float a0 = b2[j], a1 = 0.0f;
        const float* w = W2 + 64 * j;
#pragma unroll
        for (int k = 0; k < 64; k += 2) {
            a0 = fmaf(h1[k],     w[k],     a0);
            a1 = fmaf(h1[k + 1], w[k + 1], a1);
        }
        const float a = lrelu(a0 + a1);
        ld0 = fmaf(a, WLd[j],      ld0);
        ld1 = fmaf(a, WLd[64 + j], ld1);
        lo  = fmaf(a, WLo[j],      lo);
    }
    ld0 = softplus(ld0);
    ld1 = softplus(ld1);
    float4 o;
    o.x = fmaf(ld0, ld0, 1e-9f);
    o.y = ld0 * lo;
    o.z = o.y;
    o.w = fmaf(lo, lo, fmaf(ld1, ld1, 1e-9f));
    reinterpret_cast<float4*>(out)[row] = o;
}

extern "C" void kernel_launch(void* const* d_in, const int* in_sizes, int n_in,
                              void* d_out, int out_size, void* d_ws, size_t ws_size,
                              hipStream_t stream)
{
    const float* x   = (const float*)d_in[0];
    const float* W1  = (const float*)d_in[1];
    const float* b1  = (const float*)d_in[2];
    const float* W2  = (const float*)d_in[3];
    const float* b2  = (const float*)d_in[4];
    const float* WLd = (const float*)d_in[5];
    const float* bLd = (const float*)d_in[6];
    const float* WLo = (const float*)d_in[7];
    const float* bLo = (const float*)d_in[8];
    float* out = (float*)d_out;

    const int nrows = in_sizes[0] / 4;             // x is (nrows, 4) fp32
    const int nfull = nrows / ROWS_PER_BLOCK;
    const int rem   = nrows - nfull * ROWS_PER_BLOCK;

    if (nfull > 0)
        dln_mfma<<<nfull, 256, 0, stream>>>(
            x, W1, b1, W2, b2, WLd, bLd, WLo, bLo, out);
    if (rem > 0)
        dln_tail<<<(rem + 255) / 256, 256, 0, stream>>>(
            x, W1, b1, W2, b2, WLd, bLd, WLo, bLo, out,
            nfull * ROWS_PER_BLOCK, nrows);
}